// Round 5
// baseline (483.661 us; speedup 1.0000x reference)
//
#include <hip/hip_runtime.h>

// ChildSumTreeLSTMCell — round 5: register-lean fused kernel.
// 16 nodes/block, 256 threads (4 waves), 4 blocks/CU (LDS 35.6KB).
// Chunk = 4 nodes = one M=16 tile (node-major (node,child) rows) so the
// uh accumulator is lane-local per node -> f-gates + c_tild fully in regs.
// A-tile rows permuted p(n)=(n&3)*4+(n>>2) so iou-GEMM output rows match the
// lanes holding ct_acc -> final h,c written straight from registers.

typedef __attribute__((ext_vector_type(8))) short short8;
typedef __attribute__((ext_vector_type(4))) float f32x4;
typedef __attribute__((ext_vector_type(4))) unsigned short us4;

#define NN 65536

__device__ __forceinline__ unsigned short f2bf(float f) {
  unsigned int u = __float_as_uint(f);
  u += 0x7FFFu + ((u >> 16) & 1u);   // RNE
  return (unsigned short)(u >> 16);
}
__device__ __forceinline__ float bf2f(unsigned short s) {
  return __uint_as_float(((unsigned int)s) << 16);
}
__device__ __forceinline__ f32x4 mfma16(short8 a, short8 b, f32x4 c) {
  return __builtin_amdgcn_mfma_f32_16x16x32_bf16(a, b, c, 0, 0, 0);
}
__device__ __forceinline__ float sigmoidf_(float v) { return 1.0f / (1.0f + __expf(-v)); }
__device__ __forceinline__ float ftanh(float v) { return 1.0f - 2.0f / (__expf(2.0f * v) + 1.0f); }

// ---------------- weight prep ----------------
// frag layout: [kt][ct][lane][8]; lane holds B[k=kt*32+8*(lane>>4)+j][col=ct*16+(lane&15)]
__global__ void prep_all(const float* __restrict__ Wf, const float* __restrict__ Uf,
                         const float* __restrict__ Wiou, const float* __restrict__ Uiou,
                         unsigned short* __restrict__ ws) {
  int idx = blockIdx.x * 256 + threadIdx.x;          // 589824 total
  if (idx < 81920) {                                  // Bwf [10][16][64][8]
    int j = idx & 7, lane = (idx >> 3) & 63, ct = (idx >> 9) & 15, kt = idx >> 13;
    int k = kt*32 + ((lane >> 4) << 3) + j, col = ct*16 + (lane & 15);
    ws[idx] = f2bf(k < 300 ? Wf[col*300 + k] : 0.0f);
  } else if (idx < 147456) {                          // Buf [8][16][64][8]
    int i = idx - 81920;
    int j = i & 7, lane = (i >> 3) & 63, ct = (i >> 9) & 15, kt = i >> 13;
    int k = kt*32 + ((lane >> 4) << 3) + j, col = ct*16 + (lane & 15);
    ws[idx] = f2bf(Uf[col*256 + k]);
  } else {                                            // Biou [18][48][64][8]; ct = cb*3+gate
    int i = idx - 147456;
    int j = i & 7, lane = (i >> 3) & 63;
    int rest = i >> 9, ct = rest % 48, kt = rest / 48;
    int k = kt*32 + ((lane >> 4) << 3) + j;
    int g = (ct % 3)*256 + (ct/3)*16 + (lane & 15);
    float v = (k < 320) ? (k < 300 ? Wiou[g*300 + k] : 0.0f) : Uiou[g*256 + (k - 320)];
    ws[idx] = f2bf(v);
  }
}

// ---------------- fused cell ----------------
__global__ __launch_bounds__(256, 4) void fused_cell(
    const float* __restrict__ x, const float* __restrict__ h_msgs,
    const float* __restrict__ c_msgs,
    const float* __restrict__ b_iou, const float* __restrict__ b_Uiou,
    const float* __restrict__ bWf, const float* __restrict__ bUf,
    const unsigned short* __restrict__ Bwf, const unsigned short* __restrict__ Buf,
    const unsigned short* __restrict__ Biou,
    float* __restrict__ out_h, float* __restrict__ out_c) {
  __shared__ alignas(16) unsigned short Axh[16*584];  // permuted rows: x | h_tild (18688 B)
  __shared__ alignas(16) unsigned short Hm[16*264];   // (node,child) rows, one chunk (8448 B)
  __shared__ alignas(16) unsigned short wfs[16*264];  // wf+bias, true-node rows (8448 B)

  const int tid = threadIdx.x;
  const int n0 = blockIdx.x * 16;
  const int wave = tid >> 6, lane = tid & 63;
  const int lrow = lane & 15, lgrp = lane >> 4;
  const f32x4 fz = {0.0f, 0.0f, 0.0f, 0.0f};

  f32x4 hvN[4];           // in-flight h_msgs for next chunk (wave's node)
  f32x4 ct_acc[4];        // [chunk] -> elem ctb; cols wave*64+ctb*16+lrow
  float cm[4][4];         // c_msgs [child][ctb] for current chunk

  auto issue_h = [&](int chunk) {
    int node = n0 + chunk*4 + wave;
    const float* hp = h_msgs + (size_t)node*1024 + lane*4;
#pragma unroll
    for (int k = 0; k < 4; ++k) hvN[k] = *(const f32x4*)(hp + k*256);
  };
  auto write_h = [&](int chunk) {      // Hm rows wave*4+k ; h_tild -> Axh row wave*4+chunk
    f32x4 s = fz;
#pragma unroll
    for (int k = 0; k < 4; ++k) {
      us4 o;
#pragma unroll
      for (int e = 0; e < 4; ++e) { s[e] += hvN[k][e]; o[e] = f2bf(hvN[k][e]); }
      *(us4*)&Hm[(wave*4 + k)*264 + lane*4] = o;
    }
    us4 ht;
#pragma unroll
    for (int e = 0; e < 4; ++e) ht[e] = f2bf(s[e]);
    *(us4*)&Axh[(wave*4 + chunk)*584 + 320 + lane*4] = ht;
  };
  auto issue_c = [&](int chunk) {      // 16 scalars: [child][ctb], 64B-coalesced
    const float* cp = c_msgs + (size_t)(n0 + chunk*4 + lgrp)*1024 + wave*64 + lrow;
#pragma unroll
    for (int r = 0; r < 4; ++r)
#pragma unroll
      for (int ctb = 0; ctb < 4; ++ctb) cm[r][ctb] = cp[r*256 + ctb*16];
  };

  // ---- prologue: issue h0, stage x (permuted rows), write Hm0, issue h1
  issue_h(0);
  for (int i = tid; i < 16*80; i += 256) {
    int r = i / 80, c4 = i - r*80;
    f32x4 v = fz;
    if (c4 < 75) v = *(const f32x4*)&x[(size_t)(n0 + r)*300 + c4*4];
    us4 o;
#pragma unroll
    for (int e = 0; e < 4; ++e) o[e] = f2bf(v[e]);
    *(us4*)&Axh[((r & 3)*4 + (r >> 2))*584 + c4*4] = o;
  }
  write_h(0);
  issue_h(1);
  __syncthreads();                     // Axh(x) + Hm0 ready

  float bu[4];
#pragma unroll
  for (int ctb = 0; ctb < 4; ++ctb) bu[ctb] = bUf[wave*64 + ctb*16 + lrow];

  // ---- wf GEMM: [16 x 320] x [320 x 256]; wave -> cols wave*64..+63
  {
    f32x4 acc[4] = {fz, fz, fz, fz};
    const unsigned short* bp = Bwf + ((wave*4)*64 + lane)*8;
    short8 b0 = *(const short8*)bp,           b1 = *(const short8*)(bp + 512);
    short8 b2 = *(const short8*)(bp + 1024),  b3 = *(const short8*)(bp + 1536);
#pragma unroll
    for (int ks = 0; ks < 10; ++ks) {
      short8 n0b = b0, n1b = b1, n2b = b2, n3b = b3;
      if (ks < 9) {
        const unsigned short* np = Bwf + (((ks+1)*16 + wave*4)*64 + lane)*8;
        n0b = *(const short8*)np;          n1b = *(const short8*)(np + 512);
        n2b = *(const short8*)(np + 1024); n3b = *(const short8*)(np + 1536);
      }
      short8 a = *(const short8*)&Axh[lrow*584 + ks*32 + lgrp*8];
      acc[0] = mfma16(a, b0, acc[0]); acc[1] = mfma16(a, b1, acc[1]);
      acc[2] = mfma16(a, b2, acc[2]); acc[3] = mfma16(a, b3, acc[3]);
      b0 = n0b; b1 = n1b; b2 = n2b; b3 = n3b;
    }
    // C row r'=lgrp*4+r (permuted) -> true node r*4+lgrp; store by true node
#pragma unroll
    for (int ctb = 0; ctb < 4; ++ctb) {
      int col = wave*64 + ctb*16 + lrow;
      float bias = bWf[col];
#pragma unroll
      for (int r = 0; r < 4; ++r)
        wfs[(r*4 + lgrp)*264 + col] = f2bf(acc[ctb][r] + bias);
    }
  }

  // ---- 4 chunks: uh GEMM + in-register f-gates/c_tild
#pragma unroll
  for (int chunk = 0; chunk < 4; ++chunk) {
    issue_c(chunk);
    f32x4 acc[4] = {fz, fz, fz, fz};
    {
      const unsigned short* bp = Buf + ((wave*4)*64 + lane)*8;
      short8 b0 = *(const short8*)bp,          b1 = *(const short8*)(bp + 512);
      short8 b2 = *(const short8*)(bp + 1024), b3 = *(const short8*)(bp + 1536);
#pragma unroll
      for (int ks = 0; ks < 8; ++ks) {
        short8 n0b = b0, n1b = b1, n2b = b2, n3b = b3;
        if (ks < 7) {
          const unsigned short* np = Buf + (((ks+1)*16 + wave*4)*64 + lane)*8;
          n0b = *(const short8*)np;          n1b = *(const short8*)(np + 512);
          n2b = *(const short8*)(np + 1024); n3b = *(const short8*)(np + 1536);
        }
        short8 a = *(const short8*)&Hm[lrow*264 + ks*32 + lgrp*8];
        acc[0] = mfma16(a, b0, acc[0]); acc[1] = mfma16(a, b1, acc[1]);
        acc[2] = mfma16(a, b2, acc[2]); acc[3] = mfma16(a, b3, acc[3]);
        b0 = n0b; b1 = n1b; b2 = n2b; b3 = n3b;
      }
    }
    // lane holds uh for node (chunk*4+lgrp), children r, cols wave*64+ctb*16+lrow
    f32x4 ctv;
#pragma unroll
    for (int ctb = 0; ctb < 4; ++ctb) {
      int col = wave*64 + ctb*16 + lrow;
      float wfv = bf2f(wfs[(chunk*4 + lgrp)*264 + col]);
      float s = 0.0f;
#pragma unroll
      for (int r = 0; r < 4; ++r) {
        float fg = sigmoidf_(acc[ctb][r] + wfv + bu[ctb]);
        s += fg * cm[r][ctb];
      }
      ctv[ctb] = s;
    }
    ct_acc[chunk] = ctv;
    if (chunk < 3) {
      __syncthreads();                 // all waves done reading Hm(chunk)
      write_h(chunk + 1);
      if (chunk < 2) issue_h(chunk + 2);
      __syncthreads();                 // Hm(chunk+1) ready
    }
  }
  // all h_tild writes happened before the last barrier -> iou can read Axh now

  // ---- iou GEMM: [16 x 576] x [576 x 768]; wave -> col-blocks wave*4..+3, 2 passes
#pragma unroll
  for (int p = 0; p < 2; ++p) {
    f32x4 ai0 = fz, ao0 = fz, au0 = fz, ai1 = fz, ao1 = fz, au1 = fz;
    int cb0 = wave*4 + p*2;            // triples cb0, cb0+1 (6 contiguous frags)
    int col0 = cb0*16 + lrow, col1 = col0 + 16;
    float bI0 = b_iou[col0]       + b_Uiou[col0];
    float bO0 = b_iou[256 + col0] + b_Uiou[256 + col0];
    float bU0 = b_iou[512 + col0] + b_Uiou[512 + col0];
    float bI1 = b_iou[col1]       + b_Uiou[col1];
    float bO1 = b_iou[256 + col1] + b_Uiou[256 + col1];
    float bU1 = b_iou[512 + col1] + b_Uiou[512 + col1];
    const unsigned short* bp = Biou + ((size_t)(cb0*3)*64 + lane)*8;
    short8 f0 = *(const short8*)bp,          f1 = *(const short8*)(bp + 512);
    short8 f2 = *(const short8*)(bp + 1024), f3 = *(const short8*)(bp + 1536);
    short8 f4 = *(const short8*)(bp + 2048), f5 = *(const short8*)(bp + 2560);
#pragma unroll
    for (int ks = 0; ks < 18; ++ks) {
      short8 g0 = f0, g1 = f1, g2 = f2, g3 = f3, g4 = f4, g5 = f5;
      if (ks < 17) {
        const unsigned short* np = Biou + ((size_t)((ks+1)*48 + cb0*3)*64 + lane)*8;
        g0 = *(const short8*)np;          g1 = *(const short8*)(np + 512);
        g2 = *(const short8*)(np + 1024); g3 = *(const short8*)(np + 1536);
        g4 = *(const short8*)(np + 2048); g5 = *(const short8*)(np + 2560);
      }
      short8 a = *(const short8*)&Axh[lrow*584 + ks*32 + lgrp*8];
      ai0 = mfma16(a, f0, ai0); ao0 = mfma16(a, f1, ao0); au0 = mfma16(a, f2, au0);
      ai1 = mfma16(a, f3, ai1); ao1 = mfma16(a, f4, ao1); au1 = mfma16(a, f5, au1);
      f0 = g0; f1 = g1; f2 = g2; f3 = g3; f4 = g4; f5 = g5;
    }
    // C row r'=lgrp*4+r (permuted A) -> true node r*4+lgrp; ct_acc[r][p*2+jj] matches
#pragma unroll
    for (int r = 0; r < 4; ++r) {
      size_t base = (size_t)(n0 + r*4 + lgrp)*256;
      {
        float iv = sigmoidf_(ai0[r] + bI0);
        float ov = sigmoidf_(ao0[r] + bO0);
        float uv = ftanh(au0[r] + bU0);
        float c  = iv*uv + ct_acc[r][p*2];
        out_c[base + col0] = c;
        out_h[base + col0] = ov * ftanh(c);
      }
      {
        float iv = sigmoidf_(ai1[r] + bI1);
        float ov = sigmoidf_(ao1[r] + bO1);
        float uv = ftanh(au1[r] + bU1);
        float c  = iv*uv + ct_acc[r][p*2 + 1];
        out_c[base + col1] = c;
        out_h[base + col1] = ov * ftanh(c);
      }
    }
  }
}

extern "C" void kernel_launch(void* const* d_in, const int* in_sizes, int n_in,
                              void* d_out, int out_size, void* d_ws, size_t ws_size,
                              hipStream_t stream) {
  const float* x      = (const float*)d_in[0];
  const float* h_msgs = (const float*)d_in[1];
  const float* c_msgs = (const float*)d_in[2];
  const float* W_iou  = (const float*)d_in[3];
  const float* b_iou  = (const float*)d_in[4];
  const float* U_iou  = (const float*)d_in[5];
  const float* b_Uiou = (const float*)d_in[6];
  const float* W_f    = (const float*)d_in[7];
  const float* b_Wf   = (const float*)d_in[8];
  const float* U_f    = (const float*)d_in[9];
  const float* b_Uf   = (const float*)d_in[10];

  unsigned short* ws   = (unsigned short*)d_ws;
  unsigned short* Bwf  = ws;                    // [10][16][64][8]
  unsigned short* Buf  = ws + 81920;            // [8][16][64][8]
  unsigned short* Biou = ws + 147456;           // [18][48][64][8]

  float* h_slot = (float*)d_out;
  float* c_slot = h_slot + (size_t)NN*256;

  prep_all<<<2304, 256, 0, stream>>>(W_f, U_f, W_iou, U_iou, ws);
  fused_cell<<<NN/16, 256, 0, stream>>>(x, h_msgs, c_msgs, b_iou, b_Uiou,
                                        b_Wf, b_Uf, Bwf, Buf, Biou, h_slot, c_slot);
}

// Round 6
// 335.173 us; speedup vs baseline: 1.4430x; 1.4430x over previous
//
#include <hip/hip_runtime.h>

// ChildSumTreeLSTMCell — round 6: R4 structure + spill fix.
// 32 nodes/block, 512 threads (8 waves), 2 blocks/CU (LDS-capped).
// amdgpu_waves_per_eu(4,4) -> allocator targets 128 VGPRs instead of 64+spill.
// h_msgs prefetched 1 chunk ahead (16 regs); c_msgs issued same-chunk (16 regs,
// hidden under uh-GEMM + fgates). B-fragment prefetch in all GEMM loops.

typedef __attribute__((ext_vector_type(8))) short short8;
typedef __attribute__((ext_vector_type(4))) float f32x4;
typedef __attribute__((ext_vector_type(4))) unsigned short us4;
typedef __attribute__((ext_vector_type(4))) unsigned int u32x4;

#define NN 65536

__device__ __forceinline__ unsigned short f2bf(float f) {
  unsigned int u = __float_as_uint(f);
  u += 0x7FFFu + ((u >> 16) & 1u);   // RNE
  return (unsigned short)(u >> 16);
}
__device__ __forceinline__ float bf2f(unsigned short s) {
  return __uint_as_float(((unsigned int)s) << 16);
}
__device__ __forceinline__ f32x4 mfma16(short8 a, short8 b, f32x4 c) {
  return __builtin_amdgcn_mfma_f32_16x16x32_bf16(a, b, c, 0, 0, 0);
}
__device__ __forceinline__ float sigmoidf_(float v) { return 1.0f / (1.0f + __expf(-v)); }
__device__ __forceinline__ float ftanh(float v) { return 1.0f - 2.0f / (__expf(2.0f * v) + 1.0f); }

// ---------------- weight prep ----------------
// frag layout: [kt][ct][lane][8]; lane holds B[k=kt*32+8*(lane>>4)+j][col=ct*16+(lane&15)]
__global__ void prep_all(const float* __restrict__ Wf, const float* __restrict__ Uf,
                         const float* __restrict__ Wiou, const float* __restrict__ Uiou,
                         unsigned short* __restrict__ ws) {
  int idx = blockIdx.x * 256 + threadIdx.x;          // 589824 total
  if (idx < 81920) {                                  // Bwf [10][16][64][8]
    int j = idx & 7, lane = (idx >> 3) & 63, ct = (idx >> 9) & 15, kt = idx >> 13;
    int k = kt*32 + ((lane >> 4) << 3) + j, col = ct*16 + (lane & 15);
    ws[idx] = f2bf(k < 300 ? Wf[col*300 + k] : 0.0f);
  } else if (idx < 147456) {                          // Buf [8][16][64][8]
    int i = idx - 81920;
    int j = i & 7, lane = (i >> 3) & 63, ct = (i >> 9) & 15, kt = i >> 13;
    int k = kt*32 + ((lane >> 4) << 3) + j, col = ct*16 + (lane & 15);
    ws[idx] = f2bf(Uf[col*256 + k]);
  } else {                                            // Biou [18][48][64][8]; ct = cb*3+gate
    int i = idx - 147456;
    int j = i & 7, lane = (i >> 3) & 63;
    int rest = i >> 9, ct = rest % 48, kt = rest / 48;
    int k = kt*32 + ((lane >> 4) << 3) + j;
    int g = (ct % 3)*256 + (ct/3)*16 + (lane & 15);
    float v = (k < 320) ? (k < 300 ? Wiou[g*300 + k] : 0.0f) : Uiou[g*256 + (k - 320)];
    ws[idx] = f2bf(v);
  }
}

// ---------------- fused cell ----------------
__global__ __launch_bounds__(512)
__attribute__((amdgpu_waves_per_eu(4, 4)))
void fused_cell(
    const float* __restrict__ x, const float* __restrict__ h_msgs,
    const float* __restrict__ c_msgs,
    const float* __restrict__ b_iou, const float* __restrict__ b_Uiou,
    const float* __restrict__ bWf, const float* __restrict__ bUf,
    const unsigned short* __restrict__ Bwf, const unsigned short* __restrict__ Buf,
    const unsigned short* __restrict__ Biou,
    float* __restrict__ out_h, float* __restrict__ out_c) {
  __shared__ alignas(16) char smem[71168];
  unsigned short* Axh = (unsigned short*)smem;            // [32][584]  37376 B
  unsigned short* Hm  = (unsigned short*)(smem + 37376);  // [32][264]  16896 B
  unsigned short* wfs = (unsigned short*)(smem + 54272);  // [32][264]  16896 B
  unsigned int*   IUO = (unsigned int*)(smem + 37376);    // [32][260]  33280 B overlay

  const int tid = threadIdx.x;
  const int n0 = blockIdx.x * 32;
  const int wave = tid >> 6, lane = tid & 63;
  const int lrow = lane & 15, lgrp = lane >> 4;
  const int nl = wave;                 // wave owns node nl of each 8-node chunk
  const f32x4 fz = {0.0f, 0.0f, 0.0f, 0.0f};

  f32x4 hvN[4];                        // in-flight h_msgs for NEXT chunk (16 regs)
  f32x4 cmv[4];                        // current chunk c_msgs (16 regs)
  f32x4 ct_acc[4];

  auto issue_h = [&](int chunk) {      // global -> regs (issue only)
    int node = n0 + chunk*8 + nl;
    const float* hp = h_msgs + (size_t)node*1024 + lane*4;
#pragma unroll
    for (int k = 0; k < 4; ++k) hvN[k] = *(const f32x4*)(hp + k*256);
  };
  auto issue_c = [&](int chunk) {      // same-chunk issue; consumed in ctild
    int node = n0 + chunk*8 + nl;
    const float* cp = c_msgs + (size_t)node*1024 + lane*4;
#pragma unroll
    for (int k = 0; k < 4; ++k) cmv[k] = *(const f32x4*)(cp + k*256);
  };

  auto write_h = [&](int chunk) {      // regs -> Hm + h_tild -> Axh
    f32x4 s = fz;
#pragma unroll
    for (int k = 0; k < 4; ++k) {
      us4 o;
#pragma unroll
      for (int e = 0; e < 4; ++e) { s[e] += hvN[k][e]; o[e] = f2bf(hvN[k][e]); }
      *(us4*)&Hm[(nl*4 + k)*264 + lane*4] = o;
    }
    us4 ht;
#pragma unroll
    for (int e = 0; e < 4; ++e) ht[e] = f2bf(s[e]);
    *(us4*)&Axh[(chunk*8 + nl)*584 + 320 + lane*4] = ht;
  };

  auto uh_gemm = [&](f32x4 a2[2][2]) {
    const unsigned short* bp = Buf + ((wave*2)*64 + lane)*8;
    short8 b0 = *(const short8*)bp;
    short8 b1 = *(const short8*)(bp + 512);
#pragma unroll
    for (int ks = 0; ks < 8; ++ks) {
      short8 nb0 = b0, nb1 = b1;
      if (ks < 7) {
        const unsigned short* np = Buf + (((ks+1)*16 + wave*2)*64 + lane)*8;
        nb0 = *(const short8*)np;
        nb1 = *(const short8*)(np + 512);
      }
#pragma unroll
      for (int rt = 0; rt < 2; ++rt) {
        short8 a = *(const short8*)&Hm[(rt*16 + lrow)*264 + ks*32 + lgrp*8];
        a2[rt][0] = mfma16(a, b0, a2[rt][0]);
        a2[rt][1] = mfma16(a, b1, a2[rt][1]);
      }
      b0 = nb0; b1 = nb1;
    }
  };

  auto fgates = [&](int chunk, f32x4 a2[2][2]) {
#pragma unroll
    for (int ct = 0; ct < 2; ++ct) {
      int col = wave*32 + ct*16 + lrow;
      float bu = bUf[col];
#pragma unroll
      for (int rt = 0; rt < 2; ++rt) {
        float wfv = bf2f(wfs[(chunk*8 + rt*4 + lgrp)*264 + col]);
#pragma unroll
        for (int r = 0; r < 4; ++r) {
          float fg = sigmoidf_(a2[rt][ct][r] + wfv + bu);
          Hm[(rt*16 + lgrp*4 + r)*264 + col] = f2bf(fg);
        }
      }
    }
  };

  auto ctild = [&](int chunk) {        // reads Hm rows nl*4+k (wave-private rows)
    f32x4 a = fz;
#pragma unroll
    for (int k = 0; k < 4; ++k) {
      us4 fb = *(const us4*)&Hm[(nl*4 + k)*264 + lane*4];
#pragma unroll
      for (int e = 0; e < 4; ++e) a[e] += bf2f(fb[e]) * cmv[k][e];
    }
    ct_acc[chunk] = a;
  };

  // ---- prologue: issue h0, stage x, write Hm0, issue h1
  issue_h(0);
  for (int i = tid; i < 32*80; i += 512) {
    int r = i / 80, c4 = i - r*80;
    f32x4 v = fz;
    if (c4 < 75) v = *(const f32x4*)&x[(size_t)(n0 + r)*300 + c4*4];
    us4 o;
#pragma unroll
    for (int e = 0; e < 4; ++e) o[e] = f2bf(v[e]);
    *(us4*)&Axh[r*584 + c4*4] = o;
  }
  write_h(0);
  issue_h(1);
  __syncthreads();                     // Axh(x) + Hm0 ready

  // ---- wf GEMM: [32 x 320] x [320 x 256] -> wfs (bf16, +bias), wave-private cols
  {
    const unsigned short* bp = Bwf + ((wave*2)*64 + lane)*8;
    short8 b0 = *(const short8*)bp;
    short8 b1 = *(const short8*)(bp + 512);
    f32x4 w00 = fz, w01 = fz, w10 = fz, w11 = fz;
#pragma unroll
    for (int ks = 0; ks < 10; ++ks) {
      short8 nb0 = b0, nb1 = b1;
      if (ks < 9) {
        const unsigned short* np = Bwf + (((ks+1)*16 + wave*2)*64 + lane)*8;
        nb0 = *(const short8*)np;
        nb1 = *(const short8*)(np + 512);
      }
      short8 a0 = *(const short8*)&Axh[lrow*584 + ks*32 + lgrp*8];
      short8 a1 = *(const short8*)&Axh[(16 + lrow)*584 + ks*32 + lgrp*8];
      w00 = mfma16(a0, b0, w00); w10 = mfma16(a1, b0, w10);
      w01 = mfma16(a0, b1, w01); w11 = mfma16(a1, b1, w11);
      b0 = nb0; b1 = nb1;
    }
#pragma unroll
    for (int ct = 0; ct < 2; ++ct) {
      int col = wave*32 + ct*16 + lrow;
      float bias = bWf[col];
      f32x4 v0 = ct ? w01 : w00, v1 = ct ? w11 : w10;
#pragma unroll
      for (int r = 0; r < 4; ++r) {
        wfs[(lgrp*4 + r)*264 + col]      = f2bf(v0[r] + bias);
        wfs[(16 + lgrp*4 + r)*264 + col] = f2bf(v1[r] + bias);
      }
    }
  }

  // ---- 4 chunks, software-pipelined
#pragma unroll
  for (int chunk = 0; chunk < 4; ++chunk) {
    issue_c(chunk);                    // hides under uh_gemm + fgates
    f32x4 a2[2][2] = {{fz, fz}, {fz, fz}};
    uh_gemm(a2);
    __syncthreads();                   // Hm(h) reads done everywhere
    fgates(chunk, a2);
    __syncthreads();                   // f visible across waves
    ctild(chunk);                      // wave-private rows of Hm ...
    if (chunk < 3) {
      write_h(chunk + 1);              // ... overwritten by same wave: no barrier
      if (chunk < 2) issue_h(chunk + 2);
      __syncthreads();                 // Hm(next) ready
    }
  }
  __syncthreads();                     // last Hm/wfs reads done -> IUO overlay ok

  // ---- iou GEMM: [32 x 576] x [576 x 768]; wave owns 2 col-blocks x 3 gates
  {
    f32x4 aI[2][2], aO[2][2], aU[2][2];
#pragma unroll
    for (int rt = 0; rt < 2; ++rt)
#pragma unroll
      for (int cb = 0; cb < 2; ++cb) { aI[rt][cb] = fz; aO[rt][cb] = fz; aU[rt][cb] = fz; }
    const unsigned short* bp0 = Biou + ((size_t)(wave*6)*64 + lane)*8;
    short8 bi0 = *(const short8*)(bp0);
    short8 bo0 = *(const short8*)(bp0 + 512);
    short8 bu0 = *(const short8*)(bp0 + 1024);
    short8 bi1 = *(const short8*)(bp0 + 1536);
    short8 bo1 = *(const short8*)(bp0 + 2048);
    short8 bu1 = *(const short8*)(bp0 + 2560);
#pragma unroll
    for (int ks = 0; ks < 18; ++ks) {
      short8 ni0 = bi0, no0 = bo0, nu0 = bu0, ni1 = bi1, no1 = bo1, nu1 = bu1;
      if (ks < 17) {
        const unsigned short* np = Biou + ((size_t)((ks+1)*48 + wave*6)*64 + lane)*8;
        ni0 = *(const short8*)(np);
        no0 = *(const short8*)(np + 512);
        nu0 = *(const short8*)(np + 1024);
        ni1 = *(const short8*)(np + 1536);
        no1 = *(const short8*)(np + 2048);
        nu1 = *(const short8*)(np + 2560);
      }
#pragma unroll
      for (int rt = 0; rt < 2; ++rt) {
        short8 a = *(const short8*)&Axh[(rt*16 + lrow)*584 + ks*32 + lgrp*8];
        aI[rt][0] = mfma16(a, bi0, aI[rt][0]);
        aO[rt][0] = mfma16(a, bo0, aO[rt][0]);
        aU[rt][0] = mfma16(a, bu0, aU[rt][0]);
        aI[rt][1] = mfma16(a, bi1, aI[rt][1]);
        aO[rt][1] = mfma16(a, bo1, aO[rt][1]);
        aU[rt][1] = mfma16(a, bu1, aU[rt][1]);
      }
      bi0 = ni0; bo0 = no0; bu0 = nu0; bi1 = ni1; bo1 = no1; bu1 = nu1;
    }
    // gate epilogue -> IUO (packed bf16 iu | bf16 o)
#pragma unroll
    for (int cb = 0; cb < 2; ++cb) {
      int col = (wave*2 + cb)*16 + lrow;
      float bI = b_iou[col]       + b_Uiou[col];
      float bO = b_iou[256 + col] + b_Uiou[256 + col];
      float bU = b_iou[512 + col] + b_Uiou[512 + col];
#pragma unroll
      for (int rt = 0; rt < 2; ++rt)
#pragma unroll
        for (int r = 0; r < 4; ++r) {
          float iv = sigmoidf_(aI[rt][cb][r] + bI);
          float ov = sigmoidf_(aO[rt][cb][r] + bO);
          float uv = ftanh(aU[rt][cb][r] + bU);
          IUO[(rt*16 + lgrp*4 + r)*260 + col] =
              (unsigned int)f2bf(iv * uv) | ((unsigned int)f2bf(ov) << 16);
        }
    }
  }
  __syncthreads();

  // ---- final coalesced write: c = iu + c_tild; h = o*tanh(c)
#pragma unroll
  for (int chunk = 0; chunk < 4; ++chunk) {
    int nb = chunk*8 + nl;
    size_t base = (size_t)(n0 + nb)*256 + lane*4;
    u32x4 pk = *(const u32x4*)&IUO[nb*260 + lane*4];
    f32x4 hv, cvo;
#pragma unroll
    for (int e = 0; e < 4; ++e) {
      float iu = bf2f((unsigned short)(pk[e] & 0xFFFFu));
      float ov = bf2f((unsigned short)(pk[e] >> 16));
      float c  = iu + ct_acc[chunk][e];
      cvo[e] = c;
      hv[e] = ov * ftanh(c);
    }
    *(f32x4*)&out_h[base] = hv;
    *(f32x4*)&out_c[base] = cvo;
  }
}

extern "C" void kernel_launch(void* const* d_in, const int* in_sizes, int n_in,
                              void* d_out, int out_size, void* d_ws, size_t ws_size,
                              hipStream_t stream) {
  const float* x      = (const float*)d_in[0];
  const float* h_msgs = (const float*)d_in[1];
  const float* c_msgs = (const float*)d_in[2];
  const float* W_iou  = (const float*)d_in[3];
  const float* b_iou  = (const float*)d_in[4];
  const float* U_iou  = (const float*)d_in[5];
  const float* b_Uiou = (const float*)d_in[6];
  const float* W_f    = (const float*)d_in[7];
  const float* b_Wf   = (const float*)d_in[8];
  const float* U_f    = (const float*)d_in[9];
  const float* b_Uf   = (const float*)d_in[10];

  unsigned short* ws   = (unsigned short*)d_ws;
  unsigned short* Bwf  = ws;                    // [10][16][64][8]
  unsigned short* Buf  = ws + 81920;            // [8][16][64][8]
  unsigned short* Biou = ws + 147456;           // [18][48][64][8]

  float* h_slot = (float*)d_out;
  float* c_slot = h_slot + (size_t)NN*256;

  prep_all<<<2304, 256, 0, stream>>>(W_f, U_f, W_iou, U_iou, ws);
  fused_cell<<<NN/32, 512, 0, stream>>>(x, h_msgs, c_msgs, b_iou, b_Uiou,
                                        b_Wf, b_Uf, Bwf, Buf, Biou, h_slot, c_slot);
}

// Round 7
// 265.321 us; speedup vs baseline: 1.8229x; 1.2633x over previous
//
#include <hip/hip_runtime.h>

// ChildSumTreeLSTMCell — round 7: kill the register spill.
// R6 structure (32 nodes/block, 512 thr, 2 blocks/CU) with arch-VGPR demand
// cut below the 64-reg arch partition:
//   - ct_acc offloaded to global c-slot per chunk (same-lane read-back at end)
//   - c_msgs issued late (short liveness)
//   - iou GEMM in 2 passes of 3 fragments (frag+prefetch regs halved)

typedef __attribute__((ext_vector_type(8))) short short8;
typedef __attribute__((ext_vector_type(4))) float f32x4;
typedef __attribute__((ext_vector_type(4))) unsigned short us4;
typedef __attribute__((ext_vector_type(4))) unsigned int u32x4;

#define NN 65536

__device__ __forceinline__ unsigned short f2bf(float f) {
  unsigned int u = __float_as_uint(f);
  u += 0x7FFFu + ((u >> 16) & 1u);   // RNE
  return (unsigned short)(u >> 16);
}
__device__ __forceinline__ float bf2f(unsigned short s) {
  return __uint_as_float(((unsigned int)s) << 16);
}
__device__ __forceinline__ f32x4 mfma16(short8 a, short8 b, f32x4 c) {
  return __builtin_amdgcn_mfma_f32_16x16x32_bf16(a, b, c, 0, 0, 0);
}
__device__ __forceinline__ float sigmoidf_(float v) { return 1.0f / (1.0f + __expf(-v)); }
__device__ __forceinline__ float ftanh(float v) { return 1.0f - 2.0f / (__expf(2.0f * v) + 1.0f); }

// ---------------- weight prep ----------------
// frag layout: [kt][ct][lane][8]; lane holds B[k=kt*32+8*(lane>>4)+j][col=ct*16+(lane&15)]
__global__ void prep_all(const float* __restrict__ Wf, const float* __restrict__ Uf,
                         const float* __restrict__ Wiou, const float* __restrict__ Uiou,
                         unsigned short* __restrict__ ws) {
  int idx = blockIdx.x * 256 + threadIdx.x;          // 589824 total
  if (idx < 81920) {                                  // Bwf [10][16][64][8]
    int j = idx & 7, lane = (idx >> 3) & 63, ct = (idx >> 9) & 15, kt = idx >> 13;
    int k = kt*32 + ((lane >> 4) << 3) + j, col = ct*16 + (lane & 15);
    ws[idx] = f2bf(k < 300 ? Wf[col*300 + k] : 0.0f);
  } else if (idx < 147456) {                          // Buf [8][16][64][8]
    int i = idx - 81920;
    int j = i & 7, lane = (i >> 3) & 63, ct = (i >> 9) & 15, kt = i >> 13;
    int k = kt*32 + ((lane >> 4) << 3) + j, col = ct*16 + (lane & 15);
    ws[idx] = f2bf(Uf[col*256 + k]);
  } else {                                            // Biou [18][48][64][8]; ct = cb*3+gate
    int i = idx - 147456;
    int j = i & 7, lane = (i >> 3) & 63;
    int rest = i >> 9, ct = rest % 48, kt = rest / 48;
    int k = kt*32 + ((lane >> 4) << 3) + j;
    int g = (ct % 3)*256 + (ct/3)*16 + (lane & 15);
    float v = (k < 320) ? (k < 300 ? Wiou[g*300 + k] : 0.0f) : Uiou[g*256 + (k - 320)];
    ws[idx] = f2bf(v);
  }
}

// ---------------- fused cell ----------------
__global__ __launch_bounds__(512, 4) void fused_cell(
    const float* __restrict__ x, const float* __restrict__ h_msgs,
    const float* __restrict__ c_msgs,
    const float* __restrict__ b_iou, const float* __restrict__ b_Uiou,
    const float* __restrict__ bWf, const float* __restrict__ bUf,
    const unsigned short* __restrict__ Bwf, const unsigned short* __restrict__ Buf,
    const unsigned short* __restrict__ Biou,
    float* __restrict__ out_h, float* __restrict__ out_c) {
  __shared__ alignas(16) char smem[71168];
  unsigned short* Axh = (unsigned short*)smem;            // [32][584]  37376 B
  unsigned short* Hm  = (unsigned short*)(smem + 37376);  // [32][264]  16896 B
  unsigned short* wfs = (unsigned short*)(smem + 54272);  // [32][264]  16896 B
  unsigned int*   IUO = (unsigned int*)(smem + 37376);    // [32][260]  33280 B overlay

  const int tid = threadIdx.x;
  const int n0 = blockIdx.x * 32;
  const int wave = tid >> 6, lane = tid & 63;
  const int lrow = lane & 15, lgrp = lane >> 4;
  const int nl = wave;                 // wave owns node nl of each 8-node chunk
  const f32x4 fz = {0.0f, 0.0f, 0.0f, 0.0f};

  f32x4 hvN[4];                        // in-flight h_msgs for NEXT chunk (16 regs)

  auto issue_h = [&](int chunk) {      // global -> regs (issue only)
    int node = n0 + chunk*8 + nl;
    const float* hp = h_msgs + (size_t)node*1024 + lane*4;
#pragma unroll
    for (int k = 0; k < 4; ++k) hvN[k] = *(const f32x4*)(hp + k*256);
  };

  auto write_h = [&](int chunk) {      // regs -> Hm + h_tild -> Axh
    f32x4 s = fz;
#pragma unroll
    for (int k = 0; k < 4; ++k) {
      us4 o;
#pragma unroll
      for (int e = 0; e < 4; ++e) { s[e] += hvN[k][e]; o[e] = f2bf(hvN[k][e]); }
      *(us4*)&Hm[(nl*4 + k)*264 + lane*4] = o;
    }
    us4 ht;
#pragma unroll
    for (int e = 0; e < 4; ++e) ht[e] = f2bf(s[e]);
    *(us4*)&Axh[(chunk*8 + nl)*584 + 320 + lane*4] = ht;
  };

  auto uh_gemm = [&](f32x4 a2[2][2]) {
    const unsigned short* bp = Buf + ((wave*2)*64 + lane)*8;
    short8 b0 = *(const short8*)bp;
    short8 b1 = *(const short8*)(bp + 512);
#pragma unroll
    for (int ks = 0; ks < 8; ++ks) {
      short8 nb0 = b0, nb1 = b1;
      if (ks < 7) {
        const unsigned short* np = Buf + (((ks+1)*16 + wave*2)*64 + lane)*8;
        nb0 = *(const short8*)np;
        nb1 = *(const short8*)(np + 512);
      }
#pragma unroll
      for (int rt = 0; rt < 2; ++rt) {
        short8 a = *(const short8*)&Hm[(rt*16 + lrow)*264 + ks*32 + lgrp*8];
        a2[rt][0] = mfma16(a, b0, a2[rt][0]);
        a2[rt][1] = mfma16(a, b1, a2[rt][1]);
      }
      b0 = nb0; b1 = nb1;
    }
  };

  auto fgates = [&](int chunk, f32x4 a2[2][2]) {
#pragma unroll
    for (int ct = 0; ct < 2; ++ct) {
      int col = wave*32 + ct*16 + lrow;
      float bu = bUf[col];
#pragma unroll
      for (int rt = 0; rt < 2; ++rt) {
        float wfv = bf2f(wfs[(chunk*8 + rt*4 + lgrp)*264 + col]);
#pragma unroll
        for (int r = 0; r < 4; ++r) {
          float fg = sigmoidf_(a2[rt][ct][r] + wfv + bu);
          Hm[(rt*16 + lgrp*4 + r)*264 + col] = f2bf(fg);
        }
      }
    }
  };

  // ---- prologue: issue h0, stage x, write Hm0, issue h1
  issue_h(0);
  for (int i = tid; i < 32*80; i += 512) {
    int r = i / 80, c4 = i - r*80;
    f32x4 v = fz;
    if (c4 < 75) v = *(const f32x4*)&x[(size_t)(n0 + r)*300 + c4*4];
    us4 o;
#pragma unroll
    for (int e = 0; e < 4; ++e) o[e] = f2bf(v[e]);
    *(us4*)&Axh[r*584 + c4*4] = o;
  }
  write_h(0);
  issue_h(1);
  __syncthreads();                     // Axh(x) + Hm0 ready

  // ---- wf GEMM: [32 x 320] x [320 x 256] -> wfs (bf16, +bias), wave-private cols
  {
    const unsigned short* bp = Bwf + ((wave*2)*64 + lane)*8;
    short8 b0 = *(const short8*)bp;
    short8 b1 = *(const short8*)(bp + 512);
    f32x4 w00 = fz, w01 = fz, w10 = fz, w11 = fz;
#pragma unroll
    for (int ks = 0; ks < 10; ++ks) {
      short8 nb0 = b0, nb1 = b1;
      if (ks < 9) {
        const unsigned short* np = Bwf + (((ks+1)*16 + wave*2)*64 + lane)*8;
        nb0 = *(const short8*)np;
        nb1 = *(const short8*)(np + 512);
      }
      short8 a0 = *(const short8*)&Axh[lrow*584 + ks*32 + lgrp*8];
      short8 a1 = *(const short8*)&Axh[(16 + lrow)*584 + ks*32 + lgrp*8];
      w00 = mfma16(a0, b0, w00); w10 = mfma16(a1, b0, w10);
      w01 = mfma16(a0, b1, w01); w11 = mfma16(a1, b1, w11);
      b0 = nb0; b1 = nb1;
    }
#pragma unroll
    for (int ct = 0; ct < 2; ++ct) {
      int col = wave*32 + ct*16 + lrow;
      float bias = bWf[col];
      f32x4 v0 = ct ? w01 : w00, v1 = ct ? w11 : w10;
#pragma unroll
      for (int r = 0; r < 4; ++r) {
        wfs[(lgrp*4 + r)*264 + col]      = f2bf(v0[r] + bias);
        wfs[(16 + lgrp*4 + r)*264 + col] = f2bf(v1[r] + bias);
      }
    }
  }

  // ---- 4 chunks; c_tild goes straight to global c-slot (frees 16 regs)
#pragma unroll
  for (int chunk = 0; chunk < 4; ++chunk) {
    f32x4 a2[2][2] = {{fz, fz}, {fz, fz}};
    uh_gemm(a2);

    // issue c_msgs now: consumed after fgates (+barrier) -> latency hidden
    f32x4 cmv[4];
    {
      const float* cp = c_msgs + (size_t)(n0 + chunk*8 + nl)*1024 + lane*4;
#pragma unroll
      for (int k = 0; k < 4; ++k) cmv[k] = *(const f32x4*)(cp + k*256);
    }
    __syncthreads();                   // Hm(h) reads done everywhere
    fgates(chunk, a2);
    __syncthreads();                   // f visible across waves
    {                                  // c_tild: wave-private Hm rows
      f32x4 a = fz;
#pragma unroll
      for (int k = 0; k < 4; ++k) {
        us4 fb = *(const us4*)&Hm[(nl*4 + k)*264 + lane*4];
#pragma unroll
        for (int e = 0; e < 4; ++e) a[e] += bf2f(fb[e]) * cmv[k][e];
      }
      *(f32x4*)&out_c[(size_t)(n0 + chunk*8 + nl)*256 + lane*4] = a;
    }
    if (chunk < 3) {
      write_h(chunk + 1);              // same wave-private rows: no barrier
      if (chunk < 2) issue_h(chunk + 2);
      __syncthreads();                 // Hm(next) ready
    }
  }
  __syncthreads();                     // last Hm/wfs reads done -> IUO overlay ok

  // ---- iou GEMM: [32 x 576] x [576 x 768]; 2 passes of 1 col-block x 3 gates
#pragma unroll 1
  for (int p = 0; p < 2; ++p) {
    int cb = wave*2 + p;               // col-block in [0,16)
    int ct0 = cb*3;
    int col = cb*16 + lrow;
    f32x4 aI0 = fz, aO0 = fz, aU0 = fz, aI1 = fz, aO1 = fz, aU1 = fz;
    const unsigned short* bp = Biou + ((size_t)ct0*64 + lane)*8;
    short8 bi = *(const short8*)bp;
    short8 bo = *(const short8*)(bp + 512);
    short8 bu8 = *(const short8*)(bp + 1024);
#pragma unroll
    for (int ks = 0; ks < 18; ++ks) {
      short8 ni = bi, no = bo, nu = bu8;
      if (ks < 17) {
        const unsigned short* np = Biou + ((size_t)((ks+1)*48 + ct0)*64 + lane)*8;
        ni = *(const short8*)np;
        no = *(const short8*)(np + 512);
        nu = *(const short8*)(np + 1024);
      }
      short8 a0 = *(const short8*)&Axh[lrow*584 + ks*32 + lgrp*8];
      short8 a1 = *(const short8*)&Axh[(16 + lrow)*584 + ks*32 + lgrp*8];
      aI0 = mfma16(a0, bi, aI0);  aI1 = mfma16(a1, bi, aI1);
      aO0 = mfma16(a0, bo, aO0);  aO1 = mfma16(a1, bo, aO1);
      aU0 = mfma16(a0, bu8, aU0); aU1 = mfma16(a1, bu8, aU1);
      bi = ni; bo = no; bu8 = nu;
    }
    float bI = b_iou[col]       + b_Uiou[col];
    float bO = b_iou[256 + col] + b_Uiou[256 + col];
    float bU = b_iou[512 + col] + b_Uiou[512 + col];
#pragma unroll
    for (int rt = 0; rt < 2; ++rt) {
      f32x4 ai = rt ? aI1 : aI0, ao = rt ? aO1 : aO0, au = rt ? aU1 : aU0;
#pragma unroll
      for (int r = 0; r < 4; ++r) {
        float iv = sigmoidf_(ai[r] + bI);
        float ov = sigmoidf_(ao[r] + bO);
        float uv = ftanh(au[r] + bU);
        IUO[(rt*16 + lgrp*4 + r)*260 + col] =
            (unsigned int)f2bf(iv * uv) | ((unsigned int)f2bf(ov) << 16);
      }
    }
  }
  __syncthreads();

  // ---- final coalesced write: c = iu + c_tild (read back); h = o*tanh(c)
#pragma unroll
  for (int chunk = 0; chunk < 4; ++chunk) {
    int nb = chunk*8 + nl;
    size_t base = (size_t)(n0 + nb)*256 + lane*4;
    u32x4 pk = *(const u32x4*)&IUO[nb*260 + lane*4];
    f32x4 ctl = *(const f32x4*)&out_c[base];   // written by this same lane above
    f32x4 hv, cvo;
#pragma unroll
    for (int e = 0; e < 4; ++e) {
      float iu = bf2f((unsigned short)(pk[e] & 0xFFFFu));
      float ov = bf2f((unsigned short)(pk[e] >> 16));
      float c  = iu + ctl[e];
      cvo[e] = c;
      hv[e] = ov * ftanh(c);
    }
    *(f32x4*)&out_h[base] = hv;
    *(f32x4*)&out_c[base] = cvo;
  }
}

extern "C" void kernel_launch(void* const* d_in, const int* in_sizes, int n_in,
                              void* d_out, int out_size, void* d_ws, size_t ws_size,
                              hipStream_t stream) {
  const float* x      = (const float*)d_in[0];
  const float* h_msgs = (const float*)d_in[1];
  const float* c_msgs = (const float*)d_in[2];
  const float* W_iou  = (const float*)d_in[3];
  const float* b_iou  = (const float*)d_in[4];
  const float* U_iou  = (const float*)d_in[5];
  const float* b_Uiou = (const float*)d_in[6];
  const float* W_f    = (const float*)d_in[7];
  const float* b_Wf   = (const float*)d_in[8];
  const float* U_f    = (const float*)d_in[9];
  const float* b_Uf   = (const float*)d_in[10];

  unsigned short* ws   = (unsigned short*)d_ws;
  unsigned short* Bwf  = ws;                    // [10][16][64][8]
  unsigned short* Buf  = ws + 81920;            // [8][16][64][8]
  unsigned short* Biou = ws + 147456;           // [18][48][64][8]

  float* h_slot = (float*)d_out;
  float* c_slot = h_slot + (size_t)NN*256;

  prep_all<<<2304, 256, 0, stream>>>(W_f, U_f, W_iou, U_iou, ws);
  fused_cell<<<NN/32, 512, 0, stream>>>(x, h_msgs, c_msgs, b_iou, b_Uiou,
                                        b_Wf, b_Uf, Bwf, Buf, Biou, h_slot, c_slot);
}